// Round 1
// baseline (364.204 us; speedup 1.0000x reference)
//
#include <hip/hip_runtime.h>
#include <hip/hip_bf16.h>

typedef __bf16 bf16;
typedef __attribute__((ext_vector_type(4))) __bf16 bf16x4;
typedef __attribute__((ext_vector_type(8))) __bf16 bf16x8;
typedef __attribute__((ext_vector_type(4))) float f32x4;

#define D_MODEL 1024
#define NHEADS 16
#define DK 64
#define BATCH 2
#define SEQ 2048
#define NTOK (BATCH * SEQ)   // 4096

// ---------------------------------------------------------------------------
// fp32 -> bf16 conversion (vectorized: float4 in, 4x bf16 out)
// ---------------------------------------------------------------------------
__global__ void cvt_kernel(const float* __restrict__ src, bf16* __restrict__ dst, int n4) {
  int i = blockIdx.x * blockDim.x + threadIdx.x;
  if (i >= n4) return;
  float4 v = reinterpret_cast<const float4*>(src)[i];
  bf16x4 o;
  o[0] = (bf16)v.x; o[1] = (bf16)v.y; o[2] = (bf16)v.z; o[3] = (bf16)v.w;
  reinterpret_cast<bf16x4*>(dst)[i] = o;
}

// ---------------------------------------------------------------------------
// BT-GEMM: C[M,N] = A[M,K] @ Bw[N,K]^T + bias, 128x128 tile, BK=32,
// 4 waves each computing a 64x64 sub-tile via 4x4 frags of 16x16x32 MFMA.
// MODE selects epilogue layout.
// ---------------------------------------------------------------------------
#define TM 128
#define TN 128
#define BK 32

#define MODE_QK 0   // write bf16 [B,H,S,DK]
#define MODE_V  1   // write bf16 [B,H,DK,S]  (transposed for PV B-operand)
#define MODE_OUT 2  // write f32 [M, D_MODEL]

#define ASYNC_COPY16(gptr, lptr)                                                \
  __builtin_amdgcn_global_load_lds(                                             \
      (__attribute__((address_space(1))) void*)(gptr),                          \
      (__attribute__((address_space(3))) void*)(lptr), 16, 0, 0)

template <int MODE>
__global__ __launch_bounds__(256) void gemm_bt(
    const bf16* __restrict__ A,    // [M][K] row-major
    const bf16* __restrict__ Bw,   // [N][K] row-major (i.e. B transposed)
    const float* __restrict__ bias, // [N]
    void* __restrict__ out, int M, int K) {
  __shared__ bf16 As[TM][BK];  // 8 KB
  __shared__ bf16 Bs[TN][BK];  // 8 KB

  const int t = threadIdx.x;
  const int wave = t >> 6;
  const int lane = t & 63;
  const int m0 = blockIdx.x * TM;
  const int n0 = blockIdx.y * TN;
  const int wr = (wave >> 1) * 64;  // wave row offset in tile
  const int wc = (wave & 1) * 64;   // wave col offset in tile
  const int r4 = lane >> 2;         // 0..15 staging row within 16-row group
  const int c8 = (lane & 3) * 8;    // staging col elem offset (16B chunks)
  const int fr = lane & 15;         // fragment row/col
  const int fk = (lane >> 4) * 8;   // fragment k offset

  f32x4 acc[4][4] = {};

  for (int k0 = 0; k0 < K; k0 += BK) {
    // --- stage A,B tiles into LDS (wave w covers rows w*16.. and +64) ---
    ASYNC_COPY16(&A[(size_t)(m0 + wave * 16 + r4) * K + k0 + c8], &As[wave * 16][0]);
    ASYNC_COPY16(&A[(size_t)(m0 + 64 + wave * 16 + r4) * K + k0 + c8], &As[64 + wave * 16][0]);
    ASYNC_COPY16(&Bw[(size_t)(n0 + wave * 16 + r4) * K + k0 + c8], &Bs[wave * 16][0]);
    ASYNC_COPY16(&Bw[(size_t)(n0 + 64 + wave * 16 + r4) * K + k0 + c8], &Bs[64 + wave * 16][0]);
    __syncthreads();  // compiler drains vmcnt before s_barrier

    bf16x8 af[4], bfr[4];
#pragma unroll
    for (int m = 0; m < 4; m++)
      af[m] = *reinterpret_cast<const bf16x8*>(&As[wr + m * 16 + fr][fk]);
#pragma unroll
    for (int n = 0; n < 4; n++)
      bfr[n] = *reinterpret_cast<const bf16x8*>(&Bs[wc + n * 16 + fr][fk]);
#pragma unroll
    for (int m = 0; m < 4; m++)
#pragma unroll
      for (int n = 0; n < 4; n++)
        acc[m][n] = __builtin_amdgcn_mfma_f32_16x16x32_bf16(af[m], bfr[n], acc[m][n], 0, 0, 0);
    __syncthreads();
  }

  // --- epilogue: C/D layout col = lane&15, row = (lane>>4)*4 + j ---
#pragma unroll
  for (int m = 0; m < 4; m++) {
#pragma unroll
    for (int n = 0; n < 4; n++) {
      const int col = n0 + wc + n * 16 + fr;
      const float bv = bias[col];
#pragma unroll
      for (int j = 0; j < 4; j++) {
        const int row = m0 + wr + m * 16 + (lane >> 4) * 4 + j;
        const float v = acc[m][n][j] + bv;
        if (MODE == MODE_OUT) {
          reinterpret_cast<float*>(out)[(size_t)row * D_MODEL + col] = v;
        } else {
          const int b = row >> 11;           // row / SEQ
          const int s = row & (SEQ - 1);
          const int h = col >> 6;            // col / DK
          const int d = col & (DK - 1);
          if (MODE == MODE_QK)
            reinterpret_cast<bf16*>(out)[(((size_t)(b * NHEADS + h)) * SEQ + s) * DK + d] = (bf16)v;
          else  // MODE_V: transposed
            reinterpret_cast<bf16*>(out)[(((size_t)(b * NHEADS + h)) * DK + d) * SEQ + s] = (bf16)v;
        }
      }
    }
  }
}

// ---------------------------------------------------------------------------
// Flash attention forward. Grid: (SEQ/64, BATCH*NHEADS), block 256 (4 waves).
// Each wave owns 16 Q rows. KV tile = 64 rows. K/V read directly from global
// (per-head K/V = 512KB, L2-resident; LDS staging would be pure overhead).
// Online softmax with 16-lane shfl_xor reductions (all 64 lanes active).
// ---------------------------------------------------------------------------
__global__ __launch_bounds__(256) void attn_kernel(
    const bf16* __restrict__ Q,   // [B*H][SEQ][DK]
    const bf16* __restrict__ Kb,  // [B*H][SEQ][DK]
    const bf16* __restrict__ Vt,  // [B*H][DK][SEQ]
    bf16* __restrict__ X) {       // [B][SEQ][D_MODEL]
  __shared__ bf16 Pb[4][16][72];  // per-wave P buffer, +8 pad -> 2-way conflicts only

  const int lane = threadIdx.x & 63;
  const int wave = threadIdx.x >> 6;
  const int bh = blockIdx.y;
  const int b = bh >> 4, h = bh & (NHEADS - 1);
  const int q0 = blockIdx.x * 64 + wave * 16;

  const bf16* Qp = Q + ((size_t)bh * SEQ + q0) * DK;
  const bf16* Kp = Kb + (size_t)bh * SEQ * DK;
  const bf16* Vp = Vt + (size_t)bh * DK * SEQ;

  const int fr = lane & 15;
  const int fk8 = (lane >> 4) * 8;
  const int prow = (lane >> 4) * 4;

  // Q fragments, register-resident for the whole KV loop
  bf16x8 qf0 = *reinterpret_cast<const bf16x8*>(&Qp[fr * DK + fk8]);
  bf16x8 qf1 = *reinterpret_cast<const bf16x8*>(&Qp[fr * DK + 32 + fk8]);

  f32x4 acco[4] = {};
  float mrow[4], lrow[4];
#pragma unroll
  for (int i = 0; i < 4; i++) { mrow[i] = -1e30f; lrow[i] = 0.f; }
  const float scale = 0.125f;  // 1/sqrt(64)

  for (int kv0 = 0; kv0 < SEQ; kv0 += 64) {
    // ---- scores: S = Q K^T (4 col-subtiles of 16) ----
    f32x4 sa[4] = {};
#pragma unroll
    for (int ns = 0; ns < 4; ns++) {
      bf16x8 kf0 = *reinterpret_cast<const bf16x8*>(&Kp[(size_t)(kv0 + ns * 16 + fr) * DK + fk8]);
      bf16x8 kf1 = *reinterpret_cast<const bf16x8*>(&Kp[(size_t)(kv0 + ns * 16 + fr) * DK + 32 + fk8]);
      sa[ns] = __builtin_amdgcn_mfma_f32_16x16x32_bf16(qf0, kf0, sa[ns], 0, 0, 0);
      sa[ns] = __builtin_amdgcn_mfma_f32_16x16x32_bf16(qf1, kf1, sa[ns], 0, 0, 0);
    }

    // ---- online softmax (rows i=0..3 of this lane's row group) ----
    float p[4][4], alpha[4];
#pragma unroll
    for (int i = 0; i < 4; i++) {
      float s0 = sa[0][i] * scale, s1 = sa[1][i] * scale;
      float s2 = sa[2][i] * scale, s3 = sa[3][i] * scale;
      float mx = fmaxf(fmaxf(s0, s1), fmaxf(s2, s3));
#pragma unroll
      for (int off = 1; off < 16; off <<= 1) mx = fmaxf(mx, __shfl_xor(mx, off));
      const float mn = fmaxf(mrow[i], mx);
      const float a = __expf(mrow[i] - mn);
      p[0][i] = __expf(s0 - mn); p[1][i] = __expf(s1 - mn);
      p[2][i] = __expf(s2 - mn); p[3][i] = __expf(s3 - mn);
      float rs = p[0][i] + p[1][i] + p[2][i] + p[3][i];
#pragma unroll
      for (int off = 1; off < 16; off <<= 1) rs += __shfl_xor(rs, off);
      lrow[i] = lrow[i] * a + rs;
      mrow[i] = mn;
      alpha[i] = a;
    }
#pragma unroll
    for (int dc = 0; dc < 4; dc++)
#pragma unroll
      for (int i = 0; i < 4; i++) acco[dc][i] *= alpha[i];

    // ---- P -> LDS (re-layout accumulator frame to A-fragment frame) ----
#pragma unroll
    for (int ns = 0; ns < 4; ns++)
#pragma unroll
      for (int i = 0; i < 4; i++)
        Pb[wave][prow + i][ns * 16 + fr] = (bf16)p[ns][i];
    __syncthreads();  // lgkm drain: per-wave write -> cross-lane read

    bf16x8 pf0 = *reinterpret_cast<const bf16x8*>(&Pb[wave][fr][fk8]);
    bf16x8 pf1 = *reinterpret_cast<const bf16x8*>(&Pb[wave][fr][32 + fk8]);

    // ---- accumulate O += P V ----
#pragma unroll
    for (int dc = 0; dc < 4; dc++) {
      bf16x8 vf0 = *reinterpret_cast<const bf16x8*>(&Vp[(size_t)(dc * 16 + fr) * SEQ + kv0 + fk8]);
      bf16x8 vf1 = *reinterpret_cast<const bf16x8*>(&Vp[(size_t)(dc * 16 + fr) * SEQ + kv0 + 32 + fk8]);
      acco[dc] = __builtin_amdgcn_mfma_f32_16x16x32_bf16(pf0, vf0, acco[dc], 0, 0, 0);
      acco[dc] = __builtin_amdgcn_mfma_f32_16x16x32_bf16(pf1, vf1, acco[dc], 0, 0, 0);
    }
  }

  // ---- normalize and write x[b, s, h*64+d] ----
  float inv[4];
#pragma unroll
  for (int i = 0; i < 4; i++) inv[i] = 1.0f / lrow[i];
  bf16* Xp = X + ((size_t)b * SEQ + q0) * D_MODEL + h * DK;
#pragma unroll
  for (int dc = 0; dc < 4; dc++)
#pragma unroll
    for (int i = 0; i < 4; i++)
      Xp[(size_t)(prow + i) * D_MODEL + dc * 16 + fr] = (bf16)(acco[dc][i] * inv[i]);
}

// ---------------------------------------------------------------------------
extern "C" void kernel_launch(void* const* d_in, const int* in_sizes, int n_in,
                              void* d_out, int out_size, void* d_ws, size_t ws_size,
                              hipStream_t stream) {
  const float* q  = (const float*)d_in[0];
  const float* k  = (const float*)d_in[1];
  const float* v  = (const float*)d_in[2];
  const float* Wq = (const float*)d_in[3];
  const float* bq = (const float*)d_in[4];
  const float* Wk = (const float*)d_in[5];
  const float* bk = (const float*)d_in[6];
  const float* Wv = (const float*)d_in[7];
  const float* bv = (const float*)d_in[8];
  const float* Wo = (const float*)d_in[9];
  const float* bo = (const float*)d_in[10];

  char* ws = (char*)d_ws;
  size_t off = 0;
  auto alloc = [&](size_t bytes) -> void* {
    void* p = ws + off;
    off += (bytes + 255) & ~(size_t)255;
    return p;
  };
  const size_t ACT = (size_t)NTOK * D_MODEL;   // 4.19M elems
  const size_t WEL = (size_t)D_MODEL * D_MODEL;

  bf16* Xq  = (bf16*)alloc(ACT * 2);
  bf16* Xk  = (bf16*)alloc(ACT * 2);
  bf16* Xv  = (bf16*)alloc(ACT * 2);
  bf16* Wqb = (bf16*)alloc(WEL * 2);
  bf16* Wkb = (bf16*)alloc(WEL * 2);
  bf16* Wvb = (bf16*)alloc(WEL * 2);
  bf16* Wob = (bf16*)alloc(WEL * 2);
  bf16* Qb  = (bf16*)alloc(ACT * 2);
  bf16* Kbf = (bf16*)alloc(ACT * 2);
  bf16* Vtb = (bf16*)alloc(ACT * 2);
  bf16* Xa  = (bf16*)alloc(ACT * 2);

  auto cvt = [&](const float* s, bf16* d, size_t n) {
    int n4 = (int)(n / 4);
    cvt_kernel<<<dim3((n4 + 255) / 256), dim3(256), 0, stream>>>(s, d, n4);
  };
  cvt(q, Xq, ACT);
  cvt(k, Xk, ACT);
  cvt(v, Xv, ACT);
  cvt(Wq, Wqb, WEL);
  cvt(Wk, Wkb, WEL);
  cvt(Wv, Wvb, WEL);
  cvt(Wo, Wob, WEL);

  dim3 gg(NTOK / TM, D_MODEL / TN), gb(256);
  gemm_bt<MODE_QK><<<gg, gb, 0, stream>>>(Xq, Wqb, bq, Qb, NTOK, D_MODEL);
  gemm_bt<MODE_QK><<<gg, gb, 0, stream>>>(Xk, Wkb, bk, Kbf, NTOK, D_MODEL);
  gemm_bt<MODE_V><<<gg, gb, 0, stream>>>(Xv, Wvb, bv, Vtb, NTOK, D_MODEL);

  attn_kernel<<<dim3(SEQ / 64, BATCH * NHEADS), dim3(256), 0, stream>>>(Qb, Kbf, Vtb, Xa);

  gemm_bt<MODE_OUT><<<gg, gb, 0, stream>>>(Xa, Wob, bo, d_out, NTOK, D_MODEL);
}

// Round 2
// 271.035 us; speedup vs baseline: 1.3438x; 1.3438x over previous
//
#include <hip/hip_runtime.h>
#include <hip/hip_bf16.h>

typedef __bf16 bf16;
typedef __attribute__((ext_vector_type(4))) __bf16 bf16x4;
typedef __attribute__((ext_vector_type(8))) __bf16 bf16x8;
typedef __attribute__((ext_vector_type(4))) float f32x4;
typedef __attribute__((ext_vector_type(16))) float f32x16;
typedef unsigned int u32;

#define D_MODEL 1024
#define NHEADS 16
#define DK 64
#define BATCH 2
#define SEQ 2048
#define NTOK (BATCH * SEQ)   // 4096

// Q pre-scale folded into projection: 1/sqrt(64) * log2(e)  -> softmax uses exp2
#define QSCALE 0.18033688011112042f

__device__ __forceinline__ u32 cvtpk_bf16(float lo, float hi) {
  u32 r;
  asm("v_cvt_pk_bf16_f32 %0, %1, %2" : "=v"(r) : "v"(lo), "v"(hi));
  return r;
}
__device__ __forceinline__ void plswap(u32& a, u32& b) {
  asm("v_permlane32_swap_b32 %0, %1" : "+v"(a), "+v"(b));
}

// ---------------------------------------------------------------------------
// fp32 -> bf16 conversion
// ---------------------------------------------------------------------------
__global__ void cvt_kernel(const float* __restrict__ src, bf16* __restrict__ dst, int n4) {
  int i = blockIdx.x * blockDim.x + threadIdx.x;
  if (i >= n4) return;
  float4 v = reinterpret_cast<const float4*>(src)[i];
  bf16x4 o;
  o[0] = (bf16)v.x; o[1] = (bf16)v.y; o[2] = (bf16)v.z; o[3] = (bf16)v.w;
  reinterpret_cast<bf16x4*>(dst)[i] = o;
}

// ---------------------------------------------------------------------------
// BT-GEMM: C[M,N] = (A[M,K] @ Bw[N,K]^T + bias) * scale
// ---------------------------------------------------------------------------
#define TM 128
#define TN 128
#define BK 32

#define MODE_QK 0   // write bf16 [B,H,S,DK]
#define MODE_V  1   // write bf16 [B,H,DK,S]
#define MODE_OUT 2  // write f32 [M, D_MODEL]

#define ASYNC_COPY16(gptr, lptr)                                                \
  __builtin_amdgcn_global_load_lds(                                             \
      (__attribute__((address_space(1))) void*)(gptr),                          \
      (__attribute__((address_space(3))) void*)(lptr), 16, 0, 0)

template <int MODE>
__global__ __launch_bounds__(256) void gemm_bt(
    const bf16* __restrict__ A, const bf16* __restrict__ Bw,
    const float* __restrict__ bias, void* __restrict__ out, int M, int K,
    float scale) {
  __shared__ bf16 As[TM][BK];
  __shared__ bf16 Bs[TN][BK];

  const int t = threadIdx.x;
  const int wave = t >> 6;
  const int lane = t & 63;
  const int m0 = blockIdx.x * TM;
  const int n0 = blockIdx.y * TN;
  const int wr = (wave >> 1) * 64;
  const int wc = (wave & 1) * 64;
  const int r4 = lane >> 2;
  const int c8 = (lane & 3) * 8;
  const int fr = lane & 15;
  const int fk = (lane >> 4) * 8;

  f32x4 acc[4][4] = {};

  for (int k0 = 0; k0 < K; k0 += BK) {
    ASYNC_COPY16(&A[(size_t)(m0 + wave * 16 + r4) * K + k0 + c8], &As[wave * 16][0]);
    ASYNC_COPY16(&A[(size_t)(m0 + 64 + wave * 16 + r4) * K + k0 + c8], &As[64 + wave * 16][0]);
    ASYNC_COPY16(&Bw[(size_t)(n0 + wave * 16 + r4) * K + k0 + c8], &Bs[wave * 16][0]);
    ASYNC_COPY16(&Bw[(size_t)(n0 + 64 + wave * 16 + r4) * K + k0 + c8], &Bs[64 + wave * 16][0]);
    __syncthreads();

    bf16x8 af[4], bfr[4];
#pragma unroll
    for (int m = 0; m < 4; m++)
      af[m] = *reinterpret_cast<const bf16x8*>(&As[wr + m * 16 + fr][fk]);
#pragma unroll
    for (int n = 0; n < 4; n++)
      bfr[n] = *reinterpret_cast<const bf16x8*>(&Bs[wc + n * 16 + fr][fk]);
#pragma unroll
    for (int m = 0; m < 4; m++)
#pragma unroll
      for (int n = 0; n < 4; n++)
        acc[m][n] = __builtin_amdgcn_mfma_f32_16x16x32_bf16(af[m], bfr[n], acc[m][n], 0, 0, 0);
    __syncthreads();
  }

#pragma unroll
  for (int m = 0; m < 4; m++) {
#pragma unroll
    for (int n = 0; n < 4; n++) {
      const int col = n0 + wc + n * 16 + fr;
      const float bv = bias[col];
#pragma unroll
      for (int j = 0; j < 4; j++) {
        const int row = m0 + wr + m * 16 + (lane >> 4) * 4 + j;
        const float v = (acc[m][n][j] + bv) * scale;
        if (MODE == MODE_OUT) {
          reinterpret_cast<float*>(out)[(size_t)row * D_MODEL + col] = v;
        } else {
          const int b = row >> 11;
          const int s = row & (SEQ - 1);
          const int h = col >> 6;
          const int d = col & (DK - 1);
          if (MODE == MODE_QK)
            reinterpret_cast<bf16*>(out)[(((size_t)(b * NHEADS + h)) * SEQ + s) * DK + d] = (bf16)v;
          else
            reinterpret_cast<bf16*>(out)[(((size_t)(b * NHEADS + h)) * DK + d) * SEQ + s] = (bf16)v;
        }
      }
    }
  }
}

// ---------------------------------------------------------------------------
// Flash attention, swapped-operand 32x32x16 structure (m214-style).
// 4 waves/block, each wave owns 32 q rows; KV tile = 64. No LDS, no barriers.
// S^T = mfma(K, Q): lane holds 32 scores for q = lane&31.
// O^T = mfma(V^T, P^T): lane's accumulator cols are q = lane&31 -> per-lane
// scalar rescale. P redistributed in-register via cvt_pk + permlane32_swap.
// ---------------------------------------------------------------------------
#define QBLK 32
#define KVBLK 64
#define NT (SEQ / KVBLK)   // 32

__global__ __launch_bounds__(256) void attn_kernel(
    const bf16* __restrict__ Q,   // [B*H][SEQ][DK]   (pre-scaled by QSCALE)
    const bf16* __restrict__ Kb,  // [B*H][SEQ][DK]
    const bf16* __restrict__ Vt,  // [B*H][DK][SEQ]
    bf16* __restrict__ X) {       // [B][SEQ][D_MODEL]
  const int lane = threadIdx.x & 63;
  const int wave = threadIdx.x >> 6;
  const int bh = blockIdx.y;
  const int bb = bh >> 4, hh = bh & (NHEADS - 1);
  const int q0 = blockIdx.x * (QBLK * 4) + wave * QBLK;
  const int row = lane & 31, hi = lane >> 5;

  const bf16* Qp = Q + (size_t)bh * SEQ * DK;
  const bf16* Kp = Kb + (size_t)bh * SEQ * DK;
  const bf16* Vp = Vt + (size_t)bh * DK * SEQ;

  // Q fragments (B-operand): lane supplies col q=row, k = kd*16 + hi*8 + jj
  bf16x8 qf[4];
#pragma unroll
  for (int kd = 0; kd < 4; kd++)
    qf[kd] = *reinterpret_cast<const bf16x8*>(&Qp[(size_t)(q0 + row) * DK + kd * 16 + hi * 8]);

  f32x16 ot0, ot1;
#pragma unroll
  for (int r = 0; r < 16; r++) { ot0[r] = 0.f; ot1[r] = 0.f; }
  float m_run = -1e30f, l_run = 0.f;

  bf16x8 ka[2][4], kb2[2][4];

#define LOADK(dst, kv)                                                          \
  {                                                                             \
    _Pragma("unroll") for (int h = 0; h < 2; h++)                               \
        _Pragma("unroll") for (int kd = 0; kd < 4; kd++)                        \
            dst[h][kd] = *reinterpret_cast<const bf16x8*>(                      \
                &Kp[(size_t)((kv) + h * 32 + row) * DK + kd * 16 + hi * 8]);    \
  }

  LOADK(ka, 0)

  auto body = [&](bf16x8(&cur)[2][4], bf16x8(&nxt)[2][4], int t) {
    const int kv0 = t * KVBLK;
    // ---- S^T = K . Q^T : two 32-kv halves ----
    f32x16 s0, s1;
#pragma unroll
    for (int r = 0; r < 16; r++) { s0[r] = 0.f; s1[r] = 0.f; }
#pragma unroll
    for (int kd = 0; kd < 4; kd++)
      s0 = __builtin_amdgcn_mfma_f32_32x32x16_bf16(cur[0][kd], qf[kd], s0, 0, 0, 0);
#pragma unroll
    for (int kd = 0; kd < 4; kd++)
      s1 = __builtin_amdgcn_mfma_f32_32x32x16_bf16(cur[1][kd], qf[kd], s1, 0, 0, 0);

    // ---- prefetch next K tile (hidden under softmax + PV) ----
    const int kvn = (t + 1 < NT ? t + 1 : 0) * KVBLK;
    LOADK(nxt, kvn)

    // ---- V fragments for this tile (issue before softmax VALU) ----
    bf16x8 vf[2][4];
#pragma unroll
    for (int dh = 0; dh < 2; dh++)
#pragma unroll
      for (int ks = 0; ks < 4; ks++)
        vf[dh][ks] = *reinterpret_cast<const bf16x8*>(
            &Vp[(size_t)(dh * 32 + row) * SEQ + kv0 + ks * 16 + hi * 8]);

    // ---- online softmax, exp2 domain (scale folded into Q) ----
    float p[32];
#pragma unroll
    for (int r = 0; r < 16; r++) { p[r] = s0[r]; p[16 + r] = s1[r]; }
    float w16[16], w8[8], w4[4];
#pragma unroll
    for (int r = 0; r < 16; r++) w16[r] = fmaxf(p[r], p[r + 16]);
#pragma unroll
    for (int r = 0; r < 8; r++) w8[r] = fmaxf(w16[r], w16[r + 8]);
#pragma unroll
    for (int r = 0; r < 4; r++) w4[r] = fmaxf(w8[r], w8[r + 4]);
    float mx = fmaxf(fmaxf(w4[0], w4[1]), fmaxf(w4[2], w4[3]));
    mx = fmaxf(mx, __shfl_xor(mx, 32));
    const float mn = fmaxf(m_run, mx);
    const float alpha = exp2f(m_run - mn);
    m_run = mn;
#pragma unroll
    for (int r = 0; r < 32; r++) p[r] = exp2f(p[r] - mn);
    float a16[16], a8[8], a4[4];
#pragma unroll
    for (int r = 0; r < 16; r++) a16[r] = p[r] + p[r + 16];
#pragma unroll
    for (int r = 0; r < 8; r++) a8[r] = a16[r] + a16[r + 8];
#pragma unroll
    for (int r = 0; r < 4; r++) a4[r] = a8[r] + a8[r + 4];
    float rs = (a4[0] + a4[1]) + (a4[2] + a4[3]);
    rs += __shfl_xor(rs, 32);
    l_run = l_run * alpha + rs;

    // ---- rescale O^T (per-lane scalar!) ----
#pragma unroll
    for (int r = 0; r < 16; r++) { ot0[r] *= alpha; ot1[r] *= alpha; }

    // ---- pack P -> P^T B-fragments: cvt_pk + permlane32_swap ----
    u32 c[16];
#pragma unroll
    for (int i = 0; i < 8; i++) c[i] = cvtpk_bf16(p[2 * i], p[2 * i + 1]);
#pragma unroll
    for (int i = 0; i < 8; i++) c[8 + i] = cvtpk_bf16(p[16 + 2 * i], p[17 + 2 * i]);
    plswap(c[0], c[2]);  plswap(c[1], c[3]);    // ks0
    plswap(c[4], c[6]);  plswap(c[5], c[7]);    // ks1
    plswap(c[8], c[10]); plswap(c[9], c[11]);   // ks2
    plswap(c[12], c[14]); plswap(c[13], c[15]); // ks3
    bf16x8 pbv[4];
#pragma unroll
    for (int ks = 0; ks < 4; ks++) {
      union { u32 u[4]; bf16x8 v; } pk;
      pk.u[0] = c[ks * 4 + 0]; pk.u[1] = c[ks * 4 + 1];
      pk.u[2] = c[ks * 4 + 2]; pk.u[3] = c[ks * 4 + 3];
      pbv[ks] = pk.v;
    }

    // ---- O^T += V^T . P^T ----
#pragma unroll
    for (int ks = 0; ks < 4; ks++) {
      ot0 = __builtin_amdgcn_mfma_f32_32x32x16_bf16(vf[0][ks], pbv[ks], ot0, 0, 0, 0);
      ot1 = __builtin_amdgcn_mfma_f32_32x32x16_bf16(vf[1][ks], pbv[ks], ot1, 0, 0, 0);
    }
  };

  for (int t = 0; t < NT; t += 2) {
    body(ka, kb2, t);
    body(kb2, ka, t + 1);
  }

  // ---- epilogue: lane holds O^T[d][q=row]; d = 32*dh + 8*g + 4*hi + j ----
  const float inv = 1.0f / l_run;
  bf16* Xp = X + ((size_t)bb * SEQ + q0 + row) * D_MODEL + hh * DK;
#pragma unroll
  for (int g = 0; g < 4; g++) {
    bf16x4 w0, w1;
#pragma unroll
    for (int j = 0; j < 4; j++) {
      w0[j] = (bf16)(ot0[g * 4 + j] * inv);
      w1[j] = (bf16)(ot1[g * 4 + j] * inv);
    }
    *reinterpret_cast<bf16x4*>(&Xp[g * 8 + hi * 4]) = w0;
    *reinterpret_cast<bf16x4*>(&Xp[32 + g * 8 + hi * 4]) = w1;
  }
}

// ---------------------------------------------------------------------------
extern "C" void kernel_launch(void* const* d_in, const int* in_sizes, int n_in,
                              void* d_out, int out_size, void* d_ws, size_t ws_size,
                              hipStream_t stream) {
  const float* q  = (const float*)d_in[0];
  const float* k  = (const float*)d_in[1];
  const float* v  = (const float*)d_in[2];
  const float* Wq = (const float*)d_in[3];
  const float* bq = (const float*)d_in[4];
  const float* Wk = (const float*)d_in[5];
  const float* bk = (const float*)d_in[6];
  const float* Wv = (const float*)d_in[7];
  const float* bv = (const float*)d_in[8];
  const float* Wo = (const float*)d_in[9];
  const float* bo = (const float*)d_in[10];

  char* ws = (char*)d_ws;
  size_t off = 0;
  auto alloc = [&](size_t bytes) -> void* {
    void* p = ws + off;
    off += (bytes + 255) & ~(size_t)255;
    return p;
  };
  const size_t ACT = (size_t)NTOK * D_MODEL;
  const size_t WEL = (size_t)D_MODEL * D_MODEL;

  bf16* Xq  = (bf16*)alloc(ACT * 2);
  bf16* Xk  = (bf16*)alloc(ACT * 2);
  bf16* Xv  = (bf16*)alloc(ACT * 2);
  bf16* Wqb = (bf16*)alloc(WEL * 2);
  bf16* Wkb = (bf16*)alloc(WEL * 2);
  bf16* Wvb = (bf16*)alloc(WEL * 2);
  bf16* Wob = (bf16*)alloc(WEL * 2);
  bf16* Qb  = (bf16*)alloc(ACT * 2);
  bf16* Kbf = (bf16*)alloc(ACT * 2);
  bf16* Vtb = (bf16*)alloc(ACT * 2);
  bf16* Xa  = (bf16*)alloc(ACT * 2);

  auto cvt = [&](const float* s, bf16* d, size_t n) {
    int n4 = (int)(n / 4);
    cvt_kernel<<<dim3((n4 + 255) / 256), dim3(256), 0, stream>>>(s, d, n4);
  };
  cvt(q, Xq, ACT);
  cvt(k, Xk, ACT);
  cvt(v, Xv, ACT);
  cvt(Wq, Wqb, WEL);
  cvt(Wk, Wkb, WEL);
  cvt(Wv, Wvb, WEL);
  cvt(Wo, Wob, WEL);

  dim3 gg(NTOK / TM, D_MODEL / TN), gb(256);
  gemm_bt<MODE_QK><<<gg, gb, 0, stream>>>(Xq, Wqb, bq, Qb, NTOK, D_MODEL, QSCALE);
  gemm_bt<MODE_QK><<<gg, gb, 0, stream>>>(Xk, Wkb, bk, Kbf, NTOK, D_MODEL, 1.0f);
  gemm_bt<MODE_V><<<gg, gb, 0, stream>>>(Xv, Wvb, bv, Vtb, NTOK, D_MODEL, 1.0f);

  attn_kernel<<<dim3(SEQ / (QBLK * 4), BATCH * NHEADS), dim3(256), 0, stream>>>(Qb, Kbf, Vtb, Xa);

  gemm_bt<MODE_OUT><<<gg, gb, 0, stream>>>(Xa, Wob, bo, d_out, NTOK, D_MODEL, 1.0f);
}

// Round 5
// 221.967 us; speedup vs baseline: 1.6408x; 1.2211x over previous
//
#include <hip/hip_runtime.h>
#include <hip/hip_bf16.h>

typedef __bf16 bf16;
typedef __attribute__((ext_vector_type(4))) __bf16 bf16x4;
typedef __attribute__((ext_vector_type(8))) __bf16 bf16x8;
typedef __attribute__((ext_vector_type(4))) float f32x4;
typedef __attribute__((ext_vector_type(16))) float f32x16;
typedef unsigned int u32;

#define D_MODEL 1024
#define NHEADS 16
#define DK 64
#define BATCH 2
#define SEQ 2048
#define NTOK (BATCH * SEQ)   // 4096

// 1/sqrt(64) * log2(e) folded into Q projection -> softmax runs in exp2 domain
#define QSCALE 0.18033688011112042f

__device__ __forceinline__ u32 cvtpk_bf16(float lo, float hi) {
  u32 r;
  asm("v_cvt_pk_bf16_f32 %0, %1, %2" : "=v"(r) : "v"(lo), "v"(hi));
  return r;
}
__device__ __forceinline__ void plswap(u32& a, u32& b) {
  asm("v_permlane32_swap_b32 %0, %1" : "+v"(a), "+v"(b));
}
__device__ __forceinline__ float fast_exp2(float x) {
#if __has_builtin(__builtin_amdgcn_exp2f)
  return __builtin_amdgcn_exp2f(x);
#else
  return exp2f(x);
#endif
}
// Cross-half (lane ^ 32) combine — __shfl_xor (R2-proven). The permlane-based
// variant is a hazard trap: v_mov immediately before v_permlane32_swap reading
// the same reg violates the VALU->permlane wait-state the compiler can't see
// inside one asm block.
__device__ __forceinline__ float xhalf_max(float x) {
  return fmaxf(x, __shfl_xor(x, 32));
}
__device__ __forceinline__ float xhalf_add(float x) {
  return x + __shfl_xor(x, 32);
}

// ---------------------------------------------------------------------------
// fp32 -> bf16 conversions, batched launches
// ---------------------------------------------------------------------------
__global__ __launch_bounds__(256) void cvt3_kernel(
    const float* __restrict__ s0, const float* __restrict__ s1, const float* __restrict__ s2,
    bf16* __restrict__ d0, bf16* __restrict__ d1, bf16* __restrict__ d2, int n4) {
  int i = blockIdx.x * blockDim.x + threadIdx.x;
  if (i >= n4) return;
  const float* s = blockIdx.y == 0 ? s0 : blockIdx.y == 1 ? s1 : s2;
  bf16* d = blockIdx.y == 0 ? d0 : blockIdx.y == 1 ? d1 : d2;
  float4 v = reinterpret_cast<const float4*>(s)[i];
  bf16x4 o;
  o[0] = (bf16)v.x; o[1] = (bf16)v.y; o[2] = (bf16)v.z; o[3] = (bf16)v.w;
  reinterpret_cast<bf16x4*>(d)[i] = o;
}

__global__ __launch_bounds__(256) void cvt4_kernel(
    const float* __restrict__ s0, const float* __restrict__ s1,
    const float* __restrict__ s2, const float* __restrict__ s3,
    bf16* __restrict__ d0, bf16* __restrict__ d1, bf16* __restrict__ d2, bf16* __restrict__ d3,
    int n4) {
  int i = blockIdx.x * blockDim.x + threadIdx.x;
  if (i >= n4) return;
  const float* s = blockIdx.y == 0 ? s0 : blockIdx.y == 1 ? s1 : blockIdx.y == 2 ? s2 : s3;
  bf16* d = blockIdx.y == 0 ? d0 : blockIdx.y == 1 ? d1 : blockIdx.y == 2 ? d2 : d3;
  float4 v = reinterpret_cast<const float4*>(s)[i];
  bf16x4 o;
  o[0] = (bf16)v.x; o[1] = (bf16)v.y; o[2] = (bf16)v.z; o[3] = (bf16)v.w;
  reinterpret_cast<bf16x4*>(d)[i] = o;
}

// ---------------------------------------------------------------------------
// BT-GEMM core: 128x64 tile, BK=32, 4 waves in 2x2, each wave 64x32 (4x2 frags)
// ---------------------------------------------------------------------------
#define TM 128
#define TN 64
#define BK 32

#define ASYNC_COPY16(gptr, lptr)                                                \
  __builtin_amdgcn_global_load_lds(                                             \
      (__attribute__((address_space(1))) void*)(gptr),                          \
      (__attribute__((address_space(3))) void*)(lptr), 16, 0, 0)

__device__ __forceinline__ void gemm_core(
    const bf16* __restrict__ A, const bf16* __restrict__ Bw, int K,
    int m0, int n0, bf16 (*As)[BK], bf16 (*Bs)[BK], f32x4 (&acc)[4][2]) {
  const int t = threadIdx.x;
  const int wave = t >> 6;
  const int lane = t & 63;
  const int wr = (wave >> 1) * 64;
  const int wc = (wave & 1) * 32;
  const int r4 = lane >> 2;
  const int c8 = (lane & 3) * 8;
  const int fr = lane & 15;
  const int fk = (lane >> 4) * 8;

  for (int k0 = 0; k0 < K; k0 += BK) {
    ASYNC_COPY16(&A[(size_t)(m0 + wave * 16 + r4) * K + k0 + c8], &As[wave * 16][0]);
    ASYNC_COPY16(&A[(size_t)(m0 + 64 + wave * 16 + r4) * K + k0 + c8], &As[64 + wave * 16][0]);
    ASYNC_COPY16(&Bw[(size_t)(n0 + wave * 16 + r4) * K + k0 + c8], &Bs[wave * 16][0]);
    __syncthreads();

    bf16x8 af[4], bfr[2];
#pragma unroll
    for (int m = 0; m < 4; m++)
      af[m] = *reinterpret_cast<const bf16x8*>(&As[wr + m * 16 + fr][fk]);
#pragma unroll
    for (int n = 0; n < 2; n++)
      bfr[n] = *reinterpret_cast<const bf16x8*>(&Bs[wc + n * 16 + fr][fk]);
#pragma unroll
    for (int m = 0; m < 4; m++)
#pragma unroll
      for (int n = 0; n < 2; n++)
        acc[m][n] = __builtin_amdgcn_mfma_f32_16x16x32_bf16(af[m], bfr[n], acc[m][n], 0, 0, 0);
    __syncthreads();
  }
}

// Combined Q/K/V projection: grid.z selects which projection; z<2 -> [B,H,S,Dk]
// layout (Q gets QSCALE), z==2 -> V transposed [B,H,Dk,S].
struct ProjArgs {
  const bf16* A[3];
  const bf16* W[3];
  const float* bias[3];
  bf16* out[3];
};

__global__ __launch_bounds__(256) void gemm_proj(ProjArgs pa, int K) {
  __shared__ bf16 As[TM][BK];
  __shared__ bf16 Bs[TN][BK];
  const int z = blockIdx.z;
  const int m0 = blockIdx.x * TM;
  const int n0 = blockIdx.y * TN;
  f32x4 acc[4][2] = {};
  gemm_core(pa.A[z], pa.W[z], K, m0, n0, As, Bs, acc);

  const int lane = threadIdx.x & 63;
  const int wave = threadIdx.x >> 6;
  const int wr = (wave >> 1) * 64;
  const int wc = (wave & 1) * 32;
  const int fr = lane & 15;
  const float scale = (z == 0) ? QSCALE : 1.0f;
  const float* bias = pa.bias[z];
  bf16* out = pa.out[z];

#pragma unroll
  for (int m = 0; m < 4; m++) {
#pragma unroll
    for (int n = 0; n < 2; n++) {
      const int col = n0 + wc + n * 16 + fr;
      const float bv = bias[col];
#pragma unroll
      for (int j = 0; j < 4; j++) {
        const int row = m0 + wr + m * 16 + (lane >> 4) * 4 + j;
        const float v = (acc[m][n][j] + bv) * scale;
        const int b = row >> 11;
        const int s = row & (SEQ - 1);
        const int h = col >> 6;
        const int d = col & (DK - 1);
        if (z < 2)
          out[(((size_t)(b * NHEADS + h)) * SEQ + s) * DK + d] = (bf16)v;
        else
          out[(((size_t)(b * NHEADS + h)) * DK + d) * SEQ + s] = (bf16)v;
      }
    }
  }
}

__global__ __launch_bounds__(256) void gemm_out(
    const bf16* __restrict__ A, const bf16* __restrict__ Bw,
    const float* __restrict__ bias, float* __restrict__ out, int K) {
  __shared__ bf16 As[TM][BK];
  __shared__ bf16 Bs[TN][BK];
  const int m0 = blockIdx.x * TM;
  const int n0 = blockIdx.y * TN;
  f32x4 acc[4][2] = {};
  gemm_core(A, Bw, K, m0, n0, As, Bs, acc);

  const int lane = threadIdx.x & 63;
  const int wave = threadIdx.x >> 6;
  const int wr = (wave >> 1) * 64;
  const int wc = (wave & 1) * 32;
  const int fr = lane & 15;
#pragma unroll
  for (int m = 0; m < 4; m++) {
#pragma unroll
    for (int n = 0; n < 2; n++) {
      const int col = n0 + wc + n * 16 + fr;
      const float bv = bias[col];
#pragma unroll
      for (int j = 0; j < 4; j++) {
        const int row = m0 + wr + m * 16 + (lane >> 4) * 4 + j;
        out[(size_t)row * D_MODEL + col] = acc[m][n][j] + bv;
      }
    }
  }
}

// ---------------------------------------------------------------------------
// Flash attention, swapped-operand 32x32x16, 2-deep software pipeline:
// QK^T of tile t+1 (pure MFMA) issues BEFORE softmax of tile t (pure VALU).
// K double-buffered at distance 2. 1-wave blocks, no LDS, no barriers.
// ---------------------------------------------------------------------------
#define QBLK 32
#define KVBLK 64
#define NT (SEQ / KVBLK)   // 32

__global__ __launch_bounds__(64, 2) void attn_kernel(
    const bf16* __restrict__ Q,   // [B*H][SEQ][DK]  (pre-scaled)
    const bf16* __restrict__ Kb,  // [B*H][SEQ][DK]
    const bf16* __restrict__ Vt,  // [B*H][DK][SEQ]
    bf16* __restrict__ X) {       // [B][SEQ][D_MODEL]
  const int lane = threadIdx.x;
  const int bh = blockIdx.y;
  const int bb = bh >> 4, hh = bh & (NHEADS - 1);
  const int q0 = blockIdx.x * QBLK;
  const int row = lane & 31, hi = lane >> 5;

  const bf16* Qp = Q + (size_t)bh * SEQ * DK;
  const bf16* Kp = Kb + (size_t)bh * SEQ * DK;
  const bf16* Vp = Vt + (size_t)bh * DK * SEQ;

  bf16x8 qf[4];
#pragma unroll
  for (int kd = 0; kd < 4; kd++)
    qf[kd] = *reinterpret_cast<const bf16x8*>(&Qp[(size_t)(q0 + row) * DK + kd * 16 + hi * 8]);

  f32x16 ot0, ot1;
#pragma unroll
  for (int r = 0; r < 16; r++) { ot0[r] = 0.f; ot1[r] = 0.f; }
  float m_run = -1e30f, l_run = 0.f;

  bf16x8 ka[2][4], kb2[2][4];

#define LOADK(dst, kv)                                                          \
  {                                                                             \
    _Pragma("unroll") for (int hf = 0; hf < 2; hf++)                            \
        _Pragma("unroll") for (int kd = 0; kd < 4; kd++)                        \
            dst[hf][kd] = *reinterpret_cast<const bf16x8*>(                     \
                &Kp[(size_t)((kv) + hf * 32 + row) * DK + kd * 16 + hi * 8]);   \
  }

  // prologue: K[0], K[1] in flight; S[0] computed
  LOADK(ka, 0)
  LOADK(kb2, KVBLK)
  f32x16 sa0, sa1, sb0, sb1;
#pragma unroll
  for (int r = 0; r < 16; r++) { sa0[r] = 0.f; sa1[r] = 0.f; }
  __builtin_amdgcn_s_setprio(1);
#pragma unroll
  for (int kd = 0; kd < 4; kd++)
    sa0 = __builtin_amdgcn_mfma_f32_32x32x16_bf16(ka[0][kd], qf[kd], sa0, 0, 0, 0);
#pragma unroll
  for (int kd = 0; kd < 4; kd++)
    sa1 = __builtin_amdgcn_mfma_f32_32x32x16_bf16(ka[1][kd], qf[kd], sa1, 0, 0, 0);
  __builtin_amdgcn_s_setprio(0);

  // pipelined body: softmax+PV of tile t (S in SC), QK of tile t+1 (into SN,
  // K-frags in KN), prefetch K[t+2] into KL.
  auto pipe = [&](f32x16& SC0, f32x16& SC1, f32x16& SN0, f32x16& SN1,
                  bf16x8 (&KN)[2][4], bf16x8 (&KL)[2][4], int t) {
    const int kv0 = t * KVBLK;
    // --- QK^T for tile t+1 (independent of SC: MFMA overlaps softmax below) --
#pragma unroll
    for (int r = 0; r < 16; r++) { SN0[r] = 0.f; SN1[r] = 0.f; }
    __builtin_amdgcn_s_setprio(1);
#pragma unroll
    for (int kd = 0; kd < 4; kd++)
      SN0 = __builtin_amdgcn_mfma_f32_32x32x16_bf16(KN[0][kd], qf[kd], SN0, 0, 0, 0);
#pragma unroll
    for (int kd = 0; kd < 4; kd++)
      SN1 = __builtin_amdgcn_mfma_f32_32x32x16_bf16(KN[1][kd], qf[kd], SN1, 0, 0, 0);
    __builtin_amdgcn_s_setprio(0);

    // --- prefetch K[t+2] (wraps at end; result unused past last tile) ---
    const int kvn = ((t + 2) & (NT - 1)) * KVBLK;
    LOADK(KL, kvn)

    // --- V fragments for tile t (latency hidden under softmax) ---
    bf16x8 vf[2][4];
#pragma unroll
    for (int dh = 0; dh < 2; dh++)
#pragma unroll
      for (int ks = 0; ks < 4; ks++)
        vf[dh][ks] = *reinterpret_cast<const bf16x8*>(
            &Vp[(size_t)(dh * 32 + row) * SEQ + kv0 + ks * 16 + hi * 8]);

    // --- online softmax on SC (exp2 domain), rescale every tile ---
    float w16[16];
#pragma unroll
    for (int r = 0; r < 16; r++) w16[r] = fmaxf(SC0[r], SC1[r]);
#pragma unroll
    for (int r = 0; r < 8; r++) w16[r] = fmaxf(w16[r], w16[r + 8]);
#pragma unroll
    for (int r = 0; r < 4; r++) w16[r] = fmaxf(w16[r], w16[r + 4]);
    float mx = fmaxf(fmaxf(w16[0], w16[1]), fmaxf(w16[2], w16[3]));
    mx = xhalf_max(mx);
    const float mn = fmaxf(m_run, mx);
    const float alpha = fast_exp2(m_run - mn);
    m_run = mn;
    l_run *= alpha;
#pragma unroll
    for (int r = 0; r < 16; r++) { ot0[r] *= alpha; ot1[r] *= alpha; }

    float p[32];
#pragma unroll
    for (int r = 0; r < 16; r++) p[r] = fast_exp2(SC0[r] - m_run);
#pragma unroll
    for (int r = 0; r < 16; r++) p[16 + r] = fast_exp2(SC1[r] - m_run);
    float a16[16];
#pragma unroll
    for (int r = 0; r < 16; r++) a16[r] = p[r] + p[r + 16];
#pragma unroll
    for (int r = 0; r < 8; r++) a16[r] += a16[r + 8];
#pragma unroll
    for (int r = 0; r < 4; r++) a16[r] += a16[r + 4];
    float rs = (a16[0] + a16[1]) + (a16[2] + a16[3]);
    l_run += xhalf_add(rs);

    // --- pack P -> P^T B-fragments (cvt_pk + permlane32_swap) ---
    u32 c[16];
#pragma unroll
    for (int i = 0; i < 8; i++) c[i] = cvtpk_bf16(p[2 * i], p[2 * i + 1]);
#pragma unroll
    for (int i = 0; i < 8; i++) c[8 + i] = cvtpk_bf16(p[16 + 2 * i], p[17 + 2 * i]);
    plswap(c[0], c[2]);   plswap(c[1], c[3]);
    plswap(c[4], c[6]);   plswap(c[5], c[7]);
    plswap(c[8], c[10]);  plswap(c[9], c[11]);
    plswap(c[12], c[14]); plswap(c[13], c[15]);
    bf16x8 pbv[4];
#pragma unroll
    for (int ks = 0; ks < 4; ks++) {
      union { u32 u[4]; bf16x8 v; } pk;
      pk.u[0] = c[ks * 4 + 0]; pk.u[1] = c[ks * 4 + 1];
      pk.u[2] = c[ks * 4 + 2]; pk.u[3] = c[ks * 4 + 3];
      pbv[ks] = pk.v;
    }

    // --- O^T += V^T . P^T ---
    __builtin_amdgcn_s_setprio(1);
#pragma unroll
    for (int ks = 0; ks < 4; ks++) {
      ot0 = __builtin_amdgcn_mfma_f32_32x32x16_bf16(vf[0][ks], pbv[ks], ot0, 0, 0, 0);
      ot1 = __builtin_amdgcn_mfma_f32_32x32x16_bf16(vf[1][ks], pbv[ks], ot1, 0, 0, 0);
    }
    __builtin_amdgcn_s_setprio(0);
  };

  for (int t = 0; t < NT; t += 2) {
    pipe(sa0, sa1, sb0, sb1, kb2, ka, t);       // softmax tile t,   QK tile t+1
    pipe(sb0, sb1, sa0, sa1, ka, kb2, t + 1);   // softmax tile t+1, QK tile t+2
  }

  // --- epilogue: lane holds O^T[d][q=row], d = 32*dh + 8*g + 4*hi + j ---
  const float inv = 1.0f / l_run;
  bf16* Xp = X + ((size_t)bb * SEQ + q0 + row) * D_MODEL + hh * DK;
#pragma unroll
  for (int g = 0; g < 4; g++) {
    bf16x4 w0, w1;
#pragma unroll
    for (int j = 0; j < 4; j++) {
      w0[j] = (bf16)(ot0[g * 4 + j] * inv);
      w1[j] = (bf16)(ot1[g * 4 + j] * inv);
    }
    *reinterpret_cast<bf16x4*>(&Xp[g * 8 + hi * 4]) = w0;
    *reinterpret_cast<bf16x4*>(&Xp[32 + g * 8 + hi * 4]) = w1;
  }
}

// ---------------------------------------------------------------------------
extern "C" void kernel_launch(void* const* d_in, const int* in_sizes, int n_in,
                              void* d_out, int out_size, void* d_ws, size_t ws_size,
                              hipStream_t stream) {
  const float* q  = (const float*)d_in[0];
  const float* k  = (const float*)d_in[1];
  const float* v  = (const float*)d_in[2];
  const float* Wq = (const float*)d_in[3];
  const float* bq = (const float*)d_in[4];
  const float* Wk = (const float*)d_in[5];
  const float* bk = (const float*)d_in[6];
  const float* Wv = (const float*)d_in[7];
  const float* bv = (const float*)d_in[8];
  const float* Wo = (const float*)d_in[9];
  const float* bo = (const float*)d_in[10];

  char* ws = (char*)d_ws;
  size_t off = 0;
  auto alloc = [&](size_t bytes) -> void* {
    void* p = ws + off;
    off += (bytes + 255) & ~(size_t)255;
    return p;
  };
  const size_t ACT = (size_t)NTOK * D_MODEL;
  const size_t WEL = (size_t)D_MODEL * D_MODEL;

  bf16* Xq  = (bf16*)alloc(ACT * 2);
  bf16* Xk  = (bf16*)alloc(ACT * 2);
  bf16* Xv  = (bf16*)alloc(ACT * 2);
  bf16* Wqb = (bf16*)alloc(WEL * 2);
  bf16* Wkb = (bf16*)alloc(WEL * 2);
  bf16* Wvb = (bf16*)alloc(WEL * 2);
  bf16* Wob = (bf16*)alloc(WEL * 2);
  bf16* Qb  = (bf16*)alloc(ACT * 2);
  bf16* Kbf = (bf16*)alloc(ACT * 2);
  bf16* Vtb = (bf16*)alloc(ACT * 2);
  bf16* Xa  = (bf16*)alloc(ACT * 2);

  {
    int n4 = (int)(ACT / 4);
    cvt3_kernel<<<dim3((n4 + 255) / 256, 3), dim3(256), 0, stream>>>(q, k, v, Xq, Xk, Xv, n4);
  }
  {
    int n4 = (int)(WEL / 4);
    cvt4_kernel<<<dim3((n4 + 255) / 256, 4), dim3(256), 0, stream>>>(
        Wq, Wk, Wv, Wo, Wqb, Wkb, Wvb, Wob, n4);
  }

  ProjArgs pa;
  pa.A[0] = Xq;  pa.A[1] = Xk;  pa.A[2] = Xv;
  pa.W[0] = Wqb; pa.W[1] = Wkb; pa.W[2] = Wvb;
  pa.bias[0] = bq; pa.bias[1] = bk; pa.bias[2] = bv;
  pa.out[0] = Qb; pa.out[1] = Kbf; pa.out[2] = Vtb;
  gemm_proj<<<dim3(NTOK / TM, D_MODEL / TN, 3), dim3(256), 0, stream>>>(pa, D_MODEL);

  attn_kernel<<<dim3(SEQ / QBLK, BATCH * NHEADS), dim3(64), 0, stream>>>(Qb, Kbf, Vtb, Xa);

  gemm_out<<<dim3(NTOK / TM, D_MODEL / TN), dim3(256), 0, stream>>>(
      Xa, Wob, bo, (float*)d_out, D_MODEL);
}